// Round 16
// baseline (127.938 us; speedup 1.0000x reference)
//
#include <hip/hip_runtime.h>
#include <math.h>

#define NBATCH 32
#define S      49152
#define NF     24          // frames (2048 samples each)
#define NB     16          // biquads
#define NBLK   4           // blocks per batch (R9-proven best)
#define CHUNK  16          // samples per thread (R9-proven; 32 spills)
#define NCH    768         // threads per block
#define NWAVE  12          // waves per block
// R24 = R22 (62.8us best) with the per-round BARRIER replaced by per-wave
// forward-only tag slots. R23 showed DPP regressed (scan chain already
// TLP-optimal) and bank conflicts are init-phase noise. The un-tested
// mechanism on the best base: the barrier phase-aligns all 12 waves, so
// scan/fold/handshake chains stall the CU simultaneously and wave 0 cannot
// start the L2 poll until the slowest sibling converges. R24: dependencies
// are strictly forward (wave w reads sagg[j], j<w), so lane 63 publishes the
// wave aggregate to a write-once per-(stage,wave) LDS slot with a RELEASE
// tag; wave w's fold ACQUIRE-spins tags 0..w-1 in order. Wave 0 waits on
// nothing intra-block; rounds pipeline naturally (per-stage slots, no wrap,
// acyclic -> deadlock-free). S0 via per-round sflag[f]/sS0f[f] (R22
// protocol). ZERO __syncthreads in the main loop. R10/R11 tested desync on
// worse bases (47-deep chained publishes / +66 FMA matrix folds); this is
// the clean test. Health: WRITE ~7MB, VGPR <= 64, absmax 0.015625.

__device__ __forceinline__ float clampf(float x, float lo, float hi) {
    return fminf(fmaxf(x, lo), hi);
}

// 16 named scalar signal registers (SSA-guaranteed; arrays spill).
#define FOREACH_S(OP) \
    OP(s00) OP(s01) OP(s02) OP(s03) OP(s04) OP(s05) OP(s06) OP(s07) \
    OP(s08) OP(s09) OP(s10) OP(s11) OP(s12) OP(s13) OP(s14) OP(s15)

#define DECL_S(x) float x;

// Phase A step: state only.  s' = T s + b*x
#define STEPA(x) { \
    const float n1_ = fmaf(t00, ic1, fmaf(t01, ic2, b0 * (x))); \
    const float n2_ = fmaf(t10, ic1, fmaf(t11, ic2, b1 * (x))); \
    ic1 = n1_; ic2 = n2_; }

// Phase C step: output + state.  y = c0*ic1 + c1*ic2 + c2*x, in place.
#define STEPC(x) { \
    const float y_  = fmaf(c0, ic1, fmaf(c1, ic2, c2 * (x))); \
    const float n1_ = fmaf(t00, ic1, fmaf(t01, ic2, b0 * (x))); \
    const float n2_ = fmaf(t10, ic1, fmaf(t11, ic2, b1 * (x))); \
    (x) = y_; ic1 = n1_; ic2 = n2_; }

__global__ __launch_bounds__(NCH, 3)
void biquad_chain_kernel(const float* __restrict__ audio,
                         const float* __restrict__ params,
                         float* __restrict__ out,
                         unsigned int* __restrict__ ws)
{
    __shared__ __align__(16) float sc[NB][NF][16];  // affine(9) + T^16(4)
    __shared__ float4 sMw[NB][6];         // T^1024 per local frame
    __shared__ float4 sPm[NB][NWAVE];     // exclusive wave-prefix P_w
    __shared__ float4 sWm[NB][3];         // pred-quarter fold matrices W_k
    __shared__ float4 sT2048[NB][NF];     // frame aggregates (init/prefix only)
    __shared__ float  sgain[2][NF];       // [0]=in gain, [1]=out gain
    __shared__ float2 sagg2[NB][NWAVE];   // per-stage wave aggregates (write-once)
    __shared__ unsigned int stag[NB][NWAVE];  // per-stage per-wave ready tag
    __shared__ float2 sS0f[NB];           // per-stage block incoming state
    __shared__ unsigned int sflag[NB];    // per-stage S0-ready flag

    const int t       = threadIdx.x;
    // XCD co-location swizzle: all 4 quarters of a batch on one XCD.
    const int xcd     = blockIdx.x & 7;
    const int slot_   = blockIdx.x >> 3;
    const int bt      = xcd * 4 + (slot_ & 3);   // batch
    const int quarter = slot_ >> 2;              // which quarter of the signal
    const int lane    = t & 63;
    const int wave    = t >> 6;
    const int frame   = quarter * 6 + (wave >> 1);  // 2 waves per 2048-frame

    // ---------------- coefficient init (threads 0..383) ----------------
    if (t < NB * NF) {
        const int f  = t / NF;
        const int fr = t % NF;
        const float* P = params + (size_t)bt * 50 * NF;
        const float fn = P[(3 * f + 0) * NF + fr];
        const float gn = P[(3 * f + 1) * NF + fr];
        const float qn = P[(3 * f + 2) * NF + fr];

        float Q = __expf(-0.69314718f + qn * 3.4657359f);
        Q = clampf(Q, 0.1f, 100.0f);

        float lo, hi;
        int type;                        // 0 hp, 1 lp, 2 peak, 3 lowshelf, 4 highshelf
        if      (f == 0)  { lo = 20.0f;   hi = 500.0f;   type = 0; }
        else if (f == 15) { lo = 5000.0f; hi = 20000.0f; type = 1; }
        else if (f == 1)  { lo = 50.0f;   hi = 16000.0f; type = 3; }
        else if (f == 14) { lo = 50.0f;   hi = 16000.0f; type = 4; }
        else              { lo = 100.0f;  hi = 15000.0f; type = 2; }

        const float fc = __expf(__logf(lo) + fn * (__logf(hi) - __logf(lo)));
        float g_ = __tanf((float)M_PI * fc / 96000.0f);   // angle <= 0.655 rad
        g_ = clampf(g_, 1e-6f, 100.0f);
        const float gdb = -24.0f + 48.0f * gn;

        float a1, a2, a3, m0, m1, m2;
        if (type == 0 || type == 1) {
            const float k = 1.0f / Q;
            a1 = 1.0f / (1.0f + g_ * (g_ + k)); a2 = g_ * a1; a3 = g_ * a2;
            if (type == 0) { m0 = 1.0f; m1 = -k;   m2 = -1.0f; }
            else           { m0 = 0.0f; m1 = 0.0f; m2 = 1.0f;  }
        } else if (type == 2) {
            const float A = __expf(gdb * (2.30258509f / 40.0f));
            const float k = (gdb >= 0.0f) ? 1.0f / (Q * A) : A / Q;
            a1 = 1.0f / (1.0f + g_ * (g_ + k)); a2 = g_ * a1; a3 = g_ * a2;
            m0 = 1.0f; m1 = k * (A * A - 1.0f); m2 = 0.0f;
        } else {
            const float A  = __expf(gdb * (2.30258509f / 40.0f));
            const float sA = sqrtf(A);
            const float k  = 1.0f / Q;
            float gs;
            if (type == 3) gs = (gdb >= 0.0f) ? g_ / sA : g_ * sA;
            else           gs = (gdb >= 0.0f) ? g_ * sA : g_ / sA;
            a1 = 1.0f / (1.0f + gs * (gs + k)); a2 = gs * a1; a3 = gs * a2;
            if (type == 3) { m0 = 1.0f;  m1 = k * (A - 1.0f);      m2 = A * A - 1.0f; }
            else           { m0 = A * A; m1 = k * (1.0f - A) * A;  m2 = 1.0f - A * A; }
        }

        // affine per-sample form: s' = T s + b*x ; y = c0*s1 + c1*s2 + c2*x
        const float q2  = a2 * a2 + a3;
        const float t00 = 2.0f * a1 - 1.0f;
        const float t01 = -2.0f * a2;
        const float t10 = 2.0f * a1 * a2;
        const float t11 = 1.0f - 2.0f * q2;
        const float b0  = 2.0f * a2;
        const float b1  = 2.0f * q2;
        const float c0  = a1 * (m1 + m2 * a2);
        const float c1  = m2 * (1.0f - q2) - m1 * a2;
        const float c2  = m0 + m1 * a2 + m2 * q2;

        // T^16 by 4 squarings
        float u00 = t00, u01 = t01, u10 = t10, u11 = t11;
        #pragma unroll
        for (int i = 0; i < 4; i++) {
            const float n00 = u00 * u00 + u01 * u10;
            const float n01 = u00 * u01 + u01 * u11;
            const float n10 = u10 * u00 + u11 * u10;
            const float n11 = u10 * u01 + u11 * u11;
            u00 = n00; u01 = n01; u10 = n10; u11 = n11;
        }
        sc[f][fr][0] = t00; sc[f][fr][1] = t01; sc[f][fr][2] = t10; sc[f][fr][3] = t11;
        sc[f][fr][4] = b0;  sc[f][fr][5] = b1;  sc[f][fr][6] = c0;  sc[f][fr][7] = c1;
        sc[f][fr][8] = c2;  sc[f][fr][9] = u00; sc[f][fr][10] = u01; sc[f][fr][11] = u10;
        sc[f][fr][12] = u11;

        // continue squaring: T^16 -> T^1024 (6 more squarings)
        #pragma unroll
        for (int i = 0; i < 6; i++) {
            const float n00 = u00 * u00 + u01 * u10;
            const float n01 = u00 * u01 + u01 * u11;
            const float n10 = u10 * u00 + u11 * u10;
            const float n11 = u10 * u01 + u11 * u11;
            u00 = n00; u01 = n01; u10 = n10; u11 = n11;
        }
        const int lfr = fr - quarter * 6;
        if (lfr >= 0 && lfr < 6) {
            sMw[f][lfr] = make_float4(u00, u01, u10, u11);
        }
        // one more squaring: T^2048 (frame aggregate, ALL frames)
        {
            const float n00 = u00 * u00 + u01 * u10;
            const float n01 = u00 * u01 + u01 * u11;
            const float n10 = u10 * u00 + u11 * u10;
            const float n11 = u10 * u01 + u11 * u11;
            sT2048[f][fr] = make_float4(n00, n01, n10, n11);
        }
    }
    if (t >= 384 && t < 384 + 2 * NF) {
        const int idx = t - 384;
        const int which = idx / NF;     // 0 = in gain (row 48), 1 = out gain (row 49)
        const int fr    = idx % NF;
        const float* P = params + (size_t)bt * 50 * NF;
        const float p  = P[(48 + which) * NF + fr];
        const float db = -60.0f + 60.0f * p;
        sgain[which][fr] = __expf(db * (2.30258509f / 20.0f));
    }
    if (t < NB * NWAVE) stag[t / NWAVE][t % NWAVE] = 0u;
    if (t < NB) sflag[t] = 0u;
    __syncthreads();

    // ------- prefix assembly (threads 0..15, one per stage) -------
    if (t < NB) {
        const int f = t;
        // exclusive wave prefixes P_w over local frames (Q = running product)
        float q00 = 1.0f, q01 = 0.0f, q10 = 0.0f, q11 = 1.0f;
        #pragma unroll
        for (int k = 0; k < 6; k++) {
            sPm[f][2 * k] = make_float4(q00, q01, q10, q11);
            const float4 mw = sMw[f][k];
            sPm[f][2 * k + 1] = make_float4(
                mw.x * q00 + mw.y * q10, mw.x * q01 + mw.y * q11,
                mw.z * q00 + mw.w * q10, mw.z * q01 + mw.w * q11);
            const float4 g = sT2048[f][quarter * 6 + k];
            const float n00 = g.x * q00 + g.y * q10;
            const float n01 = g.x * q01 + g.y * q11;
            const float n10 = g.z * q00 + g.w * q10;
            const float n11 = g.z * q01 + g.w * q11;
            q00 = n00; q01 = n01; q10 = n10; q11 = n11;
        }
        // pred-quarter fold matrices: W_{q-1}=I ; W_k = W_{k+1} * B_{k+1}
        if (quarter > 0) {
            float r00 = 1.0f, r01 = 0.0f, r10 = 0.0f, r11 = 1.0f;
            for (int k = quarter - 1; k >= 0; k--) {
                sWm[f][k] = make_float4(r00, r01, r10, r11);
                if (k > 0) {
                    float b00 = 1.0f, b01 = 0.0f, b10 = 0.0f, b11 = 1.0f;
                    #pragma unroll
                    for (int m = 0; m < 6; m++) {
                        const float4 g = sT2048[f][6 * k + m];
                        const float n00 = g.x * b00 + g.y * b10;
                        const float n01 = g.x * b01 + g.y * b11;
                        const float n10 = g.z * b00 + g.w * b10;
                        const float n11 = g.z * b01 + g.w * b11;
                        b00 = n00; b01 = n01; b10 = n10; b11 = n11;
                    }
                    const float n00 = r00 * b00 + r01 * b10;
                    const float n01 = r00 * b01 + r01 * b11;
                    const float n10 = r10 * b00 + r11 * b10;
                    const float n11 = r10 * b01 + r11 * b11;
                    r00 = n00; r01 = n01; r10 = n10; r11 = n11;
                }
            }
        }
    }
    __syncthreads();   // last block-wide barrier (init only)

    // ---------------- load chunk (with input gain) ----------------
    FOREACH_S(DECL_S)
    {
        const float ing = sgain[0][frame];
        const float* base = audio + (size_t)bt * S
                          + (size_t)(quarter * NCH + t) * CHUNK;
        float4 q;
        q = *(const float4*)(base +  0); s00 = q.x*ing; s01 = q.y*ing; s02 = q.z*ing; s03 = q.w*ing;
        q = *(const float4*)(base +  4); s04 = q.x*ing; s05 = q.y*ing; s06 = q.z*ing; s07 = q.w*ing;
        q = *(const float4*)(base +  8); s08 = q.x*ing; s09 = q.y*ing; s10 = q.z*ing; s11 = q.w*ing;
        q = *(const float4*)(base + 12); s12 = q.x*ing; s13 = q.y*ing; s14 = q.z*ing; s15 = q.w*ing;
    }

    // ---------------- 16 cascaded stages, BARRIER-FREE ----------------
    #pragma unroll 1
    for (int f = 0; f < NB; f++) {
        const float4 q0 = *(const float4*)&sc[f][frame][0];  // t00 t01 t10 t11
        const float4 q1 = *(const float4*)&sc[f][frame][4];  // b0 b1 c0 c1
        const float4 q2 = *(const float4*)&sc[f][frame][8];  // c2 M00 M01 M10
        const float  M11v = sc[f][frame][12];
        const float t00 = q0.x, t01 = q0.y, t10 = q0.z, t11 = q0.w;
        const float b0  = q1.x, b1  = q1.y, c0  = q1.z, c1  = q1.w;
        const float c2  = q2.x;

        // Phase A: zero-state run over own chunk -> affine constant
        float ic1 = 0.0f, ic2 = 0.0f;
        FOREACH_S(STEPA)

        // constants-only Kogge-Stone: wave-uniform M = T^16, M^d squared in place
        float Md00 = q2.y, Md01 = q2.z, Md10 = q2.w, Md11 = M11v;
        float Ac0 = ic1, Ac1 = ic2;
        #pragma unroll
        for (int d = 1; d < 64; d <<= 1) {
            const float lc0 = __shfl_up(Ac0, d);
            const float lc1 = __shfl_up(Ac1, d);
            if (lane >= d) {
                Ac0 = fmaf(Md00, lc0, fmaf(Md01, lc1, Ac0));
                Ac1 = fmaf(Md10, lc0, fmaf(Md11, lc1, Ac1));
            }
            const float n00 = Md00 * Md00 + Md01 * Md10;
            const float n01 = Md00 * Md01 + Md01 * Md11;
            const float n10 = Md10 * Md00 + Md11 * Md10;
            const float n11 = Md10 * Md01 + Md11 * Md11;
            Md00 = n00; Md01 = n01; Md10 = n10; Md11 = n11;
        }
        // Ac at lane 63 = wave aggregate constant

        // publish own aggregate immediately (write-once per-stage slot)
        if (lane == 63) {
            sagg2[f][wave] = make_float2(Ac0, Ac1);
            __hip_atomic_store(&stag[f][wave], 1u, __ATOMIC_RELEASE,
                               __HIP_MEMORY_SCOPE_WORKGROUP);
        }

        // ce = exclusive constants (latency overlaps the fold below)
        float ce0 = __shfl_up(Ac0, 1);
        float ce1 = __shfl_up(Ac1, 1);
        if (lane == 0) { ce0 = 0.0f; ce1 = 0.0f; }

        const unsigned int tag = (unsigned int)(f + 1);
        unsigned int* stagebase = ws + ((size_t)(bt * NB + f) * NBLK) * 8;

        // -------- per-wave exclusive-prefix fold with forward-only spins ----
        float Pc0 = 0.0f, Pc1 = 0.0f;
        for (int j = 0; j < wave; j++) {   // wave-uniform trip count
            while (__hip_atomic_load(&stag[f][j], __ATOMIC_ACQUIRE,
                                     __HIP_MEMORY_SCOPE_WORKGROUP) != 1u)
                __builtin_amdgcn_s_sleep(1);
            const float2 a = sagg2[f][j];
            const float4 mw = sMw[f][j >> 1];
            const float n0 = fmaf(mw.x, Pc0, fmaf(mw.y, Pc1, a.x));
            const float n1 = fmaf(mw.z, Pc0, fmaf(mw.w, Pc1, a.y));
            Pc0 = n0; Pc1 = n1;
        }

        // -------- wave 11: block-inclusive from own registers -> publish ----
        if (wave == NWAVE - 1 && quarter < NBLK - 1 && lane == 63) {
            const float4 mw = sMw[f][(NWAVE - 1) >> 1];
            const float i0 = fmaf(mw.x, Pc0, fmaf(mw.y, Pc1, Ac0));
            const float i1 = fmaf(mw.z, Pc0, fmaf(mw.w, Pc1, Ac1));
            unsigned int* slot = stagebase + quarter * 8;
            float* dp = (float*)(slot + 1);
            __hip_atomic_store(&dp[0], i0, __ATOMIC_RELAXED, __HIP_MEMORY_SCOPE_AGENT);
            __hip_atomic_store(&dp[1], i1, __ATOMIC_RELAXED, __HIP_MEMORY_SCOPE_AGENT);
            __hip_atomic_store(slot, tag, __ATOMIC_RELEASE, __HIP_MEMORY_SCOPE_AGENT);
        }

        // -------- block incoming state S0 (single poller: wave 0) -----------
        float S0x = 0.0f, S0y = 0.0f;
        if (quarter > 0) {
            if (wave == 0) {
                float ux = 0.0f, uy = 0.0f;
                if (lane < quarter) {
                    unsigned int* slot = stagebase + lane * 8;
                    while (__hip_atomic_load(slot, __ATOMIC_ACQUIRE, __HIP_MEMORY_SCOPE_AGENT) != tag) {
                        __builtin_amdgcn_s_sleep(1);
                    }
                    const float* dp = (const float*)(slot + 1);
                    const float cx = __hip_atomic_load(&dp[0], __ATOMIC_RELAXED, __HIP_MEMORY_SCOPE_AGENT);
                    const float cy = __hip_atomic_load(&dp[1], __ATOMIC_RELAXED, __HIP_MEMORY_SCOPE_AGENT);
                    const float4 w = sWm[f][lane];
                    ux = fmaf(w.x, cx, w.y * cy);
                    uy = fmaf(w.z, cx, w.w * cy);
                }
                S0x = __shfl(ux, 0);
                S0y = __shfl(uy, 0);
                if (quarter > 1) { S0x += __shfl(ux, 1); S0y += __shfl(uy, 1); }
                if (quarter > 2) { S0x += __shfl(ux, 2); S0y += __shfl(uy, 2); }
                if (lane == 0) {
                    sS0f[f] = make_float2(S0x, S0y);
                    __hip_atomic_store(&sflag[f], 1u, __ATOMIC_RELEASE,
                                       __HIP_MEMORY_SCOPE_WORKGROUP);
                }
            } else {
                while (__hip_atomic_load(&sflag[f], __ATOMIC_ACQUIRE,
                                         __HIP_MEMORY_SCOPE_WORKGROUP) != 1u)
                    __builtin_amdgcn_s_sleep(1);
                const float2 sb = sS0f[f];
                S0x = sb.x; S0y = sb.y;
            }
        }

        // -------- incoming wave state v = P_w * S0 + Pc_w (local compute) ---
        const float4 pm = sPm[f][wave];
        const float vx = fmaf(pm.x, S0x, fmaf(pm.y, S0y, Pc0));
        const float vy = fmaf(pm.z, S0x, fmaf(pm.w, S0y, Pc1));

        // -------- distribute: ic = M^lane * v + ce (binexp, reg squaring) ---
        float w0 = vx, w1 = vy;
        float p00 = q2.y, p01 = q2.z, p10 = q2.w, p11 = M11v;
        #pragma unroll
        for (int b = 0; b < 6; b++) {
            if (lane & (1 << b)) {
                const float nw0 = fmaf(p00, w0, p01 * w1);
                const float nw1 = fmaf(p10, w0, p11 * w1);
                w0 = nw0; w1 = nw1;
            }
            if (b < 5) {
                const float n00 = p00 * p00 + p01 * p10;
                const float n01 = p00 * p01 + p01 * p11;
                const float n10 = p10 * p00 + p11 * p10;
                const float n11 = p10 * p01 + p11 * p11;
                p00 = n00; p01 = n01; p10 = n10; p11 = n11;
            }
        }
        ic1 = w0 + ce0;
        ic2 = w1 + ce1;

        // Phase C: true run from incoming state, write outputs in place
        FOREACH_S(STEPC)
    }

    // ---------------- store (with output gain) ----------------
    {
        const float og = sgain[1][frame];
        float* base = out + (size_t)bt * S + (size_t)(quarter * NCH + t) * CHUNK;
        float4 q;
        q.x = s00*og; q.y = s01*og; q.z = s02*og; q.w = s03*og; *(float4*)(base +  0) = q;
        q.x = s04*og; q.y = s05*og; q.z = s06*og; q.w = s07*og; *(float4*)(base +  4) = q;
        q.x = s08*og; q.y = s09*og; q.z = s10*og; q.w = s11*og; *(float4*)(base +  8) = q;
        q.x = s12*og; q.y = s13*og; q.z = s14*og; q.w = s15*og; *(float4*)(base + 12) = q;
    }
}

extern "C" void kernel_launch(void* const* d_in, const int* in_sizes, int n_in,
                              void* d_out, int out_size, void* d_ws, size_t ws_size,
                              hipStream_t stream)
{
    const float* audio  = (const float*)d_in[0];
    const float* params = (const float*)d_in[1];
    float* out = (float*)d_out;
    unsigned int* ws = (unsigned int*)d_ws;
    biquad_chain_kernel<<<NBLK * NBATCH, NCH, 0, stream>>>(audio, params, out, ws);
}

// Round 17
// 112.961 us; speedup vs baseline: 1.1326x; 1.1326x over previous
//
#include <hip/hip_runtime.h>
#include <math.h>

#define NBATCH 32
#define S      49152
#define NF     24          // frames (2048 samples each)
#define NB     16          // biquads
#define NBLK   4           // blocks per batch (R9-proven best)
#define CHUNK  16          // samples per thread (R9-proven; 32 spills)
#define NCH    768         // threads per block
#define NWAVE  12          // waves per block
// R25 = R22 (62.8us best) + SUPERPOSITION Phase C. R24 re-confirmed:
// s_barrier is the cheapest sync (every spin-replacement regressed). The
// working gradient is round work/serial-chain reduction (R16 -3.5, R22
// -8.7). R22 runs TWO 16-sample recurrences per round (A: state, C:
// output+state). Superposition: y_k = y0_k + rho_k*ic, rho_k = c_state*T^k
// is PARAM-ONLY (precomputed at init, 12KB LDS). R25 runs ONE recurrence
// per round (zero-state outputs y0 in place + wave constant for KS), then
// the post-sync work is 32 INDEPENDENT FMAs (was a serial recurrence).
// -96 VALU/lane/round, -1 recurrence/round, sample loop moves pre-barrier.
// This is STEPF-fusion's goal without its register-pressure cost.
// NUMERICS WATCH: FP-reordered (algebraically exact); absmax must stay
// <= 0.015625, else revert to R22 as final.
// Health: WRITE ~7MB, VGPR <= 64.

__device__ __forceinline__ float clampf(float x, float lo, float hi) {
    return fminf(fmaxf(x, lo), hi);
}

// 16 named scalar signal registers (SSA-guaranteed; arrays spill).
#define FOREACH_S(OP) \
    OP(s00) OP(s01) OP(s02) OP(s03) OP(s04) OP(s05) OP(s06) OP(s07) \
    OP(s08) OP(s09) OP(s10) OP(s11) OP(s12) OP(s13) OP(s14) OP(s15)

#define DECL_S(x) float x;

// Zero-state run: output + state in one loop (ic starts at 0).
#define STEPY(x) { \
    const float y_  = fmaf(c0, ic1, fmaf(c1, ic2, c2 * (x))); \
    const float n1_ = fmaf(t00, ic1, fmaf(t01, ic2, b0 * (x))); \
    const float n2_ = fmaf(t10, ic1, fmaf(t11, ic2, b1 * (x))); \
    (x) = y_; ic1 = n1_; ic2 = n2_; }

__global__ __launch_bounds__(NCH, 3)
void biquad_chain_kernel(const float* __restrict__ audio,
                         const float* __restrict__ params,
                         float* __restrict__ out,
                         unsigned int* __restrict__ ws)
{
    __shared__ __align__(16) float sc[NB][NF][16];  // affine(9) + T^16(4)
    __shared__ float4 sMw[NB][6];         // T^1024 per local frame
    __shared__ float4 sPm[NB][NWAVE];     // exclusive wave-prefix P_w
    __shared__ float4 sWm[NB][3];         // pred-quarter fold matrices W_k
    __shared__ float4 sT2048[NB][NF];     // frame aggregates (init/prefix only)
    __shared__ float2 srho[NB][6][16];    // rho_k = c_state * T^k (local frames)
    __shared__ float  sgain[2][NF];       // [0]=in gain, [1]=out gain
    __shared__ float2 sagg[2][NWAVE];     // runtime wave constants (dbuf)
    __shared__ float2 sS0;                // block incoming state (wave-0 publish)
    __shared__ unsigned int sflag[NB];    // per-stage S0-ready flag

    const int t       = threadIdx.x;
    // XCD co-location swizzle: all 4 quarters of a batch on one XCD.
    const int xcd     = blockIdx.x & 7;
    const int slot_   = blockIdx.x >> 3;
    const int bt      = xcd * 4 + (slot_ & 3);   // batch
    const int quarter = slot_ >> 2;              // which quarter of the signal
    const int lane    = t & 63;
    const int wave    = t >> 6;
    const int lf      = wave >> 1;               // local frame 0..5
    const int frame   = quarter * 6 + lf;        // global frame

    // ---------------- coefficient init (threads 0..383) ----------------
    if (t < NB * NF) {
        const int f  = t / NF;
        const int fr = t % NF;
        const float* P = params + (size_t)bt * 50 * NF;
        const float fn = P[(3 * f + 0) * NF + fr];
        const float gn = P[(3 * f + 1) * NF + fr];
        const float qn = P[(3 * f + 2) * NF + fr];

        float Q = __expf(-0.69314718f + qn * 3.4657359f);
        Q = clampf(Q, 0.1f, 100.0f);

        float lo, hi;
        int type;                        // 0 hp, 1 lp, 2 peak, 3 lowshelf, 4 highshelf
        if      (f == 0)  { lo = 20.0f;   hi = 500.0f;   type = 0; }
        else if (f == 15) { lo = 5000.0f; hi = 20000.0f; type = 1; }
        else if (f == 1)  { lo = 50.0f;   hi = 16000.0f; type = 3; }
        else if (f == 14) { lo = 50.0f;   hi = 16000.0f; type = 4; }
        else              { lo = 100.0f;  hi = 15000.0f; type = 2; }

        const float fc = __expf(__logf(lo) + fn * (__logf(hi) - __logf(lo)));
        float g_ = __tanf((float)M_PI * fc / 96000.0f);   // angle <= 0.655 rad
        g_ = clampf(g_, 1e-6f, 100.0f);
        const float gdb = -24.0f + 48.0f * gn;

        float a1, a2, a3, m0, m1, m2;
        if (type == 0 || type == 1) {
            const float k = 1.0f / Q;
            a1 = 1.0f / (1.0f + g_ * (g_ + k)); a2 = g_ * a1; a3 = g_ * a2;
            if (type == 0) { m0 = 1.0f; m1 = -k;   m2 = -1.0f; }
            else           { m0 = 0.0f; m1 = 0.0f; m2 = 1.0f;  }
        } else if (type == 2) {
            const float A = __expf(gdb * (2.30258509f / 40.0f));
            const float k = (gdb >= 0.0f) ? 1.0f / (Q * A) : A / Q;
            a1 = 1.0f / (1.0f + g_ * (g_ + k)); a2 = g_ * a1; a3 = g_ * a2;
            m0 = 1.0f; m1 = k * (A * A - 1.0f); m2 = 0.0f;
        } else {
            const float A  = __expf(gdb * (2.30258509f / 40.0f));
            const float sA = sqrtf(A);
            const float k  = 1.0f / Q;
            float gs;
            if (type == 3) gs = (gdb >= 0.0f) ? g_ / sA : g_ * sA;
            else           gs = (gdb >= 0.0f) ? g_ * sA : g_ / sA;
            a1 = 1.0f / (1.0f + gs * (gs + k)); a2 = gs * a1; a3 = gs * a2;
            if (type == 3) { m0 = 1.0f;  m1 = k * (A - 1.0f);      m2 = A * A - 1.0f; }
            else           { m0 = A * A; m1 = k * (1.0f - A) * A;  m2 = 1.0f - A * A; }
        }

        // affine per-sample form: s' = T s + b*x ; y = c0*s1 + c1*s2 + c2*x
        const float q2  = a2 * a2 + a3;
        const float t00 = 2.0f * a1 - 1.0f;
        const float t01 = -2.0f * a2;
        const float t10 = 2.0f * a1 * a2;
        const float t11 = 1.0f - 2.0f * q2;
        const float b0  = 2.0f * a2;
        const float b1  = 2.0f * q2;
        const float c0  = a1 * (m1 + m2 * a2);
        const float c1  = m2 * (1.0f - q2) - m1 * a2;
        const float c2  = m0 + m1 * a2 + m2 * q2;

        const int lfr = fr - quarter * 6;
        const bool loc = (lfr >= 0 && lfr < 6);

        // rho_k = c_state * T^k (row-vector chain), local frames only
        if (loc) {
            float r0 = c0, r1 = c1;
            #pragma unroll
            for (int k = 0; k < 16; k++) {
                srho[f][lfr][k] = make_float2(r0, r1);
                const float n0 = r0 * t00 + r1 * t10;
                const float n1 = r0 * t01 + r1 * t11;
                r0 = n0; r1 = n1;
            }
        }

        // T^16 by 4 squarings
        float u00 = t00, u01 = t01, u10 = t10, u11 = t11;
        #pragma unroll
        for (int i = 0; i < 4; i++) {
            const float n00 = u00 * u00 + u01 * u10;
            const float n01 = u00 * u01 + u01 * u11;
            const float n10 = u10 * u00 + u11 * u10;
            const float n11 = u10 * u01 + u11 * u11;
            u00 = n00; u01 = n01; u10 = n10; u11 = n11;
        }
        sc[f][fr][0] = t00; sc[f][fr][1] = t01; sc[f][fr][2] = t10; sc[f][fr][3] = t11;
        sc[f][fr][4] = b0;  sc[f][fr][5] = b1;  sc[f][fr][6] = c0;  sc[f][fr][7] = c1;
        sc[f][fr][8] = c2;  sc[f][fr][9] = u00; sc[f][fr][10] = u01; sc[f][fr][11] = u10;
        sc[f][fr][12] = u11;

        // continue squaring: T^16 -> T^1024 (6 more squarings)
        #pragma unroll
        for (int i = 0; i < 6; i++) {
            const float n00 = u00 * u00 + u01 * u10;
            const float n01 = u00 * u01 + u01 * u11;
            const float n10 = u10 * u00 + u11 * u10;
            const float n11 = u10 * u01 + u11 * u11;
            u00 = n00; u01 = n01; u10 = n10; u11 = n11;
        }
        if (loc) {
            sMw[f][lfr] = make_float4(u00, u01, u10, u11);
        }
        // one more squaring: T^2048 (frame aggregate, ALL frames)
        {
            const float n00 = u00 * u00 + u01 * u10;
            const float n01 = u00 * u01 + u01 * u11;
            const float n10 = u10 * u00 + u11 * u10;
            const float n11 = u10 * u01 + u11 * u11;
            sT2048[f][fr] = make_float4(n00, n01, n10, n11);
        }
    }
    if (t >= 384 && t < 384 + 2 * NF) {
        const int idx = t - 384;
        const int which = idx / NF;     // 0 = in gain (row 48), 1 = out gain (row 49)
        const int fr    = idx % NF;
        const float* P = params + (size_t)bt * 50 * NF;
        const float p  = P[(48 + which) * NF + fr];
        const float db = -60.0f + 60.0f * p;
        sgain[which][fr] = __expf(db * (2.30258509f / 20.0f));
    }
    if (t < NB) sflag[t] = 0u;
    __syncthreads();

    // ------- prefix assembly (threads 0..15, one per stage) -------
    if (t < NB) {
        const int f = t;
        // exclusive wave prefixes P_w over local frames (Q = running product)
        float q00 = 1.0f, q01 = 0.0f, q10 = 0.0f, q11 = 1.0f;
        #pragma unroll
        for (int k = 0; k < 6; k++) {
            sPm[f][2 * k] = make_float4(q00, q01, q10, q11);
            const float4 mw = sMw[f][k];
            sPm[f][2 * k + 1] = make_float4(
                mw.x * q00 + mw.y * q10, mw.x * q01 + mw.y * q11,
                mw.z * q00 + mw.w * q10, mw.z * q01 + mw.w * q11);
            const float4 g = sT2048[f][quarter * 6 + k];
            const float n00 = g.x * q00 + g.y * q10;
            const float n01 = g.x * q01 + g.y * q11;
            const float n10 = g.z * q00 + g.w * q10;
            const float n11 = g.z * q01 + g.w * q11;
            q00 = n00; q01 = n01; q10 = n10; q11 = n11;
        }
        // pred-quarter fold matrices: W_{q-1}=I ; W_k = W_{k+1} * B_{k+1}
        if (quarter > 0) {
            float r00 = 1.0f, r01 = 0.0f, r10 = 0.0f, r11 = 1.0f;
            for (int k = quarter - 1; k >= 0; k--) {
                sWm[f][k] = make_float4(r00, r01, r10, r11);
                if (k > 0) {
                    float b00 = 1.0f, b01 = 0.0f, b10 = 0.0f, b11 = 1.0f;
                    #pragma unroll
                    for (int m = 0; m < 6; m++) {
                        const float4 g = sT2048[f][6 * k + m];
                        const float n00 = g.x * b00 + g.y * b10;
                        const float n01 = g.x * b01 + g.y * b11;
                        const float n10 = g.z * b00 + g.w * b10;
                        const float n11 = g.z * b01 + g.w * b11;
                        b00 = n00; b01 = n01; b10 = n10; b11 = n11;
                    }
                    const float n00 = r00 * b00 + r01 * b10;
                    const float n01 = r00 * b01 + r01 * b11;
                    const float n10 = r10 * b00 + r11 * b10;
                    const float n11 = r10 * b01 + r11 * b11;
                    r00 = n00; r01 = n01; r10 = n10; r11 = n11;
                }
            }
        }
    }
    __syncthreads();

    // ---------------- load chunk (with input gain) ----------------
    FOREACH_S(DECL_S)
    {
        const float ing = sgain[0][frame];
        const float* base = audio + (size_t)bt * S
                          + (size_t)(quarter * NCH + t) * CHUNK;
        float4 q;
        q = *(const float4*)(base +  0); s00 = q.x*ing; s01 = q.y*ing; s02 = q.z*ing; s03 = q.w*ing;
        q = *(const float4*)(base +  4); s04 = q.x*ing; s05 = q.y*ing; s06 = q.z*ing; s07 = q.w*ing;
        q = *(const float4*)(base +  8); s08 = q.x*ing; s09 = q.y*ing; s10 = q.z*ing; s11 = q.w*ing;
        q = *(const float4*)(base + 12); s12 = q.x*ing; s13 = q.y*ing; s14 = q.z*ing; s15 = q.w*ing;
    }

    // ---------------- 16 cascaded stages ----------------
    #pragma unroll 1
    for (int f = 0; f < NB; f++) {
        const float4 q0 = *(const float4*)&sc[f][frame][0];  // t00 t01 t10 t11
        const float4 q1 = *(const float4*)&sc[f][frame][4];  // b0 b1 c0 c1
        const float4 q2 = *(const float4*)&sc[f][frame][8];  // c2 M00 M01 M10
        const float  M11v = sc[f][frame][12];
        const float t00 = q0.x, t01 = q0.y, t10 = q0.z, t11 = q0.w;
        const float b0  = q1.x, b1  = q1.y, c0  = q1.z, c1  = q1.w;
        const float c2  = q2.x;

        // ONE recurrence: zero-state outputs y0 (in place) + zero-state state
        float ic1 = 0.0f, ic2 = 0.0f;
        FOREACH_S(STEPY)

        // constants-only Kogge-Stone: wave-uniform M = T^16, M^d squared in place
        float Md00 = q2.y, Md01 = q2.z, Md10 = q2.w, Md11 = M11v;
        float Ac0 = ic1, Ac1 = ic2;
        #pragma unroll
        for (int d = 1; d < 64; d <<= 1) {
            const float lc0 = __shfl_up(Ac0, d);
            const float lc1 = __shfl_up(Ac1, d);
            if (lane >= d) {
                Ac0 = fmaf(Md00, lc0, fmaf(Md01, lc1, Ac0));
                Ac1 = fmaf(Md10, lc0, fmaf(Md11, lc1, Ac1));
            }
            const float n00 = Md00 * Md00 + Md01 * Md10;
            const float n01 = Md00 * Md01 + Md01 * Md11;
            const float n10 = Md10 * Md00 + Md11 * Md10;
            const float n11 = Md10 * Md01 + Md11 * Md11;
            Md00 = n00; Md01 = n01; Md10 = n10; Md11 = n11;
        }
        // Ac at lane 63 = wave aggregate constant

        const int buf = f & 1;
        if (lane == 63) sagg[buf][wave] = make_float2(Ac0, Ac1);

        // ce = exclusive constants -- issue pre-barrier, latency hides under it
        float ce0 = __shfl_up(Ac0, 1);
        float ce1 = __shfl_up(Ac1, 1);
        if (lane == 0) { ce0 = 0.0f; ce1 = 0.0f; }

        __syncthreads();   // the ONE barrier per round (sagg[buf] ready)

        const unsigned int tag = (unsigned int)(f + 1);
        unsigned int* stagebase = ws + ((size_t)(bt * NB + f) * NBLK) * 8;

        // -------- per-wave exclusive-prefix constant fold (parallel) --------
        float Pc0 = 0.0f, Pc1 = 0.0f;
        #pragma unroll
        for (int j = 0; j < NWAVE - 1; j++) {
            if (j < wave) {
                const float2 a = sagg[buf][j];
                const float4 mw = sMw[f][j >> 1];
                const float n0 = fmaf(mw.x, Pc0, fmaf(mw.y, Pc1, a.x));
                const float n1 = fmaf(mw.z, Pc0, fmaf(mw.w, Pc1, a.y));
                Pc0 = n0; Pc1 = n1;
            }
        }

        // -------- wave 11: block-inclusive from own registers -> publish ----
        if (wave == NWAVE - 1 && quarter < NBLK - 1 && lane == 63) {
            const float4 mw = sMw[f][(NWAVE - 1) >> 1];
            const float i0 = fmaf(mw.x, Pc0, fmaf(mw.y, Pc1, Ac0));
            const float i1 = fmaf(mw.z, Pc0, fmaf(mw.w, Pc1, Ac1));
            unsigned int* slot = stagebase + quarter * 8;
            float* dp = (float*)(slot + 1);
            __hip_atomic_store(&dp[0], i0, __ATOMIC_RELAXED, __HIP_MEMORY_SCOPE_AGENT);
            __hip_atomic_store(&dp[1], i1, __ATOMIC_RELAXED, __HIP_MEMORY_SCOPE_AGENT);
            __hip_atomic_store(slot, tag, __ATOMIC_RELEASE, __HIP_MEMORY_SCOPE_AGENT);
        }

        // -------- block incoming state S0 (single poller: wave 0) -----------
        float S0x = 0.0f, S0y = 0.0f;
        if (quarter > 0) {
            if (wave == 0) {
                float ux = 0.0f, uy = 0.0f;
                if (lane < quarter) {
                    unsigned int* slot = stagebase + lane * 8;
                    while (__hip_atomic_load(slot, __ATOMIC_ACQUIRE, __HIP_MEMORY_SCOPE_AGENT) != tag) {
                        __builtin_amdgcn_s_sleep(1);
                    }
                    const float* dp = (const float*)(slot + 1);
                    const float cx = __hip_atomic_load(&dp[0], __ATOMIC_RELAXED, __HIP_MEMORY_SCOPE_AGENT);
                    const float cy = __hip_atomic_load(&dp[1], __ATOMIC_RELAXED, __HIP_MEMORY_SCOPE_AGENT);
                    const float4 w = sWm[f][lane];
                    ux = fmaf(w.x, cx, w.y * cy);
                    uy = fmaf(w.z, cx, w.w * cy);
                }
                S0x = __shfl(ux, 0);
                S0y = __shfl(uy, 0);
                if (quarter > 1) { S0x += __shfl(ux, 1); S0y += __shfl(uy, 1); }
                if (quarter > 2) { S0x += __shfl(ux, 2); S0y += __shfl(uy, 2); }
                if (lane == 0) {
                    sS0 = make_float2(S0x, S0y);
                    __hip_atomic_store(&sflag[f], tag, __ATOMIC_RELEASE,
                                       __HIP_MEMORY_SCOPE_WORKGROUP);
                }
            } else {
                while (__hip_atomic_load(&sflag[f], __ATOMIC_ACQUIRE,
                                         __HIP_MEMORY_SCOPE_WORKGROUP) != tag)
                    __builtin_amdgcn_s_sleep(1);
                const float2 sb = sS0;
                S0x = sb.x; S0y = sb.y;
            }
        }

        // -------- incoming wave state v = P_w * S0 + Pc_w (local compute) ---
        const float4 pm = sPm[f][wave];
        const float vx = fmaf(pm.x, S0x, fmaf(pm.y, S0y, Pc0));
        const float vy = fmaf(pm.z, S0x, fmaf(pm.w, S0y, Pc1));

        // -------- distribute: ic = M^lane * v + ce (binexp, reg squaring) ---
        float w0 = vx, w1 = vy;
        float p00 = q2.y, p01 = q2.z, p10 = q2.w, p11 = M11v;
        #pragma unroll
        for (int b = 0; b < 6; b++) {
            if (lane & (1 << b)) {
                const float nw0 = fmaf(p00, w0, p01 * w1);
                const float nw1 = fmaf(p10, w0, p11 * w1);
                w0 = nw0; w1 = nw1;
            }
            if (b < 5) {
                const float n00 = p00 * p00 + p01 * p10;
                const float n01 = p00 * p01 + p01 * p11;
                const float n10 = p10 * p00 + p11 * p10;
                const float n11 = p10 * p01 + p11 * p11;
                p00 = n00; p01 = n01; p10 = n10; p11 = n11;
            }
        }
        const float icf1 = w0 + ce0;
        const float icf2 = w1 + ce1;

        // -------- superposition correction: s_k += rho_k * ic (independent) -
        const float2* rr = srho[f][lf];
        { const float2 r = rr[ 0]; s00 = fmaf(r.x, icf1, fmaf(r.y, icf2, s00)); }
        { const float2 r = rr[ 1]; s01 = fmaf(r.x, icf1, fmaf(r.y, icf2, s01)); }
        { const float2 r = rr[ 2]; s02 = fmaf(r.x, icf1, fmaf(r.y, icf2, s02)); }
        { const float2 r = rr[ 3]; s03 = fmaf(r.x, icf1, fmaf(r.y, icf2, s03)); }
        { const float2 r = rr[ 4]; s04 = fmaf(r.x, icf1, fmaf(r.y, icf2, s04)); }
        { const float2 r = rr[ 5]; s05 = fmaf(r.x, icf1, fmaf(r.y, icf2, s05)); }
        { const float2 r = rr[ 6]; s06 = fmaf(r.x, icf1, fmaf(r.y, icf2, s06)); }
        { const float2 r = rr[ 7]; s07 = fmaf(r.x, icf1, fmaf(r.y, icf2, s07)); }
        { const float2 r = rr[ 8]; s08 = fmaf(r.x, icf1, fmaf(r.y, icf2, s08)); }
        { const float2 r = rr[ 9]; s09 = fmaf(r.x, icf1, fmaf(r.y, icf2, s09)); }
        { const float2 r = rr[10]; s10 = fmaf(r.x, icf1, fmaf(r.y, icf2, s10)); }
        { const float2 r = rr[11]; s11 = fmaf(r.x, icf1, fmaf(r.y, icf2, s11)); }
        { const float2 r = rr[12]; s12 = fmaf(r.x, icf1, fmaf(r.y, icf2, s12)); }
        { const float2 r = rr[13]; s13 = fmaf(r.x, icf1, fmaf(r.y, icf2, s13)); }
        { const float2 r = rr[14]; s14 = fmaf(r.x, icf1, fmaf(r.y, icf2, s14)); }
        { const float2 r = rr[15]; s15 = fmaf(r.x, icf1, fmaf(r.y, icf2, s15)); }
    }

    // ---------------- store (with output gain) ----------------
    {
        const float og = sgain[1][frame];
        float* base = out + (size_t)bt * S + (size_t)(quarter * NCH + t) * CHUNK;
        float4 q;
        q.x = s00*og; q.y = s01*og; q.z = s02*og; q.w = s03*og; *(float4*)(base +  0) = q;
        q.x = s04*og; q.y = s05*og; q.z = s06*og; q.w = s07*og; *(float4*)(base +  4) = q;
        q.x = s08*og; q.y = s09*og; q.z = s10*og; q.w = s11*og; *(float4*)(base +  8) = q;
        q.x = s12*og; q.y = s13*og; q.z = s14*og; q.w = s15*og; *(float4*)(base + 12) = q;
    }
}

extern "C" void kernel_launch(void* const* d_in, const int* in_sizes, int n_in,
                              void* d_out, int out_size, void* d_ws, size_t ws_size,
                              hipStream_t stream)
{
    const float* audio  = (const float*)d_in[0];
    const float* params = (const float*)d_in[1];
    float* out = (float*)d_out;
    unsigned int* ws = (unsigned int*)d_ws;
    biquad_chain_kernel<<<NBLK * NBATCH, NCH, 0, stream>>>(audio, params, out, ws);
}

// Round 18
// 111.785 us; speedup vs baseline: 1.1445x; 1.0105x over previous
//
#include <hip/hip_runtime.h>
#include <math.h>

#define NBATCH 32
#define S      49152
#define NF     24          // frames (2048 samples each)
#define NB     16          // biquads
#define NBLK   4           // blocks per batch (R9-proven best)
#define CHUNK  16          // samples per thread (R9-proven; 32 spills)
#define NCH    768         // threads per block
#define NWAVE  12          // waves per block
// R26 = R22 verbatim (62.8us, session best) -- FINAL REVERT.
// Session ledger (18 experiments): sync-topology changes (R10/R11/R20/R24)
// all regress -> hw s_barrier is the cheapest sync; parallelism/fan scaling
// (R12/R13/R15/R21) all regress; round-count fusion (R14/R17) spills or
// regresses; cross-lane primitive swaps (R18/R19/R23) null; work reduction
// is the only working gradient (R16 -3.5us, R22 -8.7us) and is exhausted
// (R25 superposition null: LDS reads near the sync point repay the VALU
// savings). R22 structure: one barrier/round; every wave folds its own
// exclusive-prefix constant from sagg (parallel, precomputed sMw); wave 11
// publishes block-inclusive from registers; wave 0 single-polls pred
// quarters (parallel lane polls + precomputed sWm fold) and posts 2-float
// S0; all waves compute v locally; binexp distribute with register
// squaring; ce shfl issued pre-barrier. All combine matrices param-only,
// precomputed at init. Health: WRITE ~7MB, VGPR 56, absmax 0.015625.

__device__ __forceinline__ float clampf(float x, float lo, float hi) {
    return fminf(fmaxf(x, lo), hi);
}

// 16 named scalar signal registers (SSA-guaranteed; arrays spill).
#define FOREACH_S(OP) \
    OP(s00) OP(s01) OP(s02) OP(s03) OP(s04) OP(s05) OP(s06) OP(s07) \
    OP(s08) OP(s09) OP(s10) OP(s11) OP(s12) OP(s13) OP(s14) OP(s15)

#define DECL_S(x) float x;

// Phase A step: state only.  s' = T s + b*x
#define STEPA(x) { \
    const float n1_ = fmaf(t00, ic1, fmaf(t01, ic2, b0 * (x))); \
    const float n2_ = fmaf(t10, ic1, fmaf(t11, ic2, b1 * (x))); \
    ic1 = n1_; ic2 = n2_; }

// Phase C step: output + state.  y = c0*ic1 + c1*ic2 + c2*x, in place.
#define STEPC(x) { \
    const float y_  = fmaf(c0, ic1, fmaf(c1, ic2, c2 * (x))); \
    const float n1_ = fmaf(t00, ic1, fmaf(t01, ic2, b0 * (x))); \
    const float n2_ = fmaf(t10, ic1, fmaf(t11, ic2, b1 * (x))); \
    (x) = y_; ic1 = n1_; ic2 = n2_; }

__global__ __launch_bounds__(NCH, 3)
void biquad_chain_kernel(const float* __restrict__ audio,
                         const float* __restrict__ params,
                         float* __restrict__ out,
                         unsigned int* __restrict__ ws)
{
    __shared__ __align__(16) float sc[NB][NF][16];  // affine(9) + T^16(4)
    __shared__ float4 sMw[NB][6];         // T^1024 per local frame
    __shared__ float4 sPm[NB][NWAVE];     // exclusive wave-prefix P_w
    __shared__ float4 sWm[NB][3];         // pred-quarter fold matrices W_k
    __shared__ float4 sT2048[NB][NF];     // frame aggregates (init/prefix only)
    __shared__ float  sgain[2][NF];       // [0]=in gain, [1]=out gain
    __shared__ float2 sagg[2][NWAVE];     // runtime wave constants (dbuf)
    __shared__ float2 sS0;                // block incoming state (wave-0 publish)
    __shared__ unsigned int sflag[NB];    // per-stage S0-ready flag

    const int t       = threadIdx.x;
    // XCD co-location swizzle: all 4 quarters of a batch on one XCD.
    const int xcd     = blockIdx.x & 7;
    const int slot_   = blockIdx.x >> 3;
    const int bt      = xcd * 4 + (slot_ & 3);   // batch
    const int quarter = slot_ >> 2;              // which quarter of the signal
    const int lane    = t & 63;
    const int wave    = t >> 6;
    const int frame   = quarter * 6 + (wave >> 1);  // 2 waves per 2048-frame

    // ---------------- coefficient init (threads 0..383) ----------------
    if (t < NB * NF) {
        const int f  = t / NF;
        const int fr = t % NF;
        const float* P = params + (size_t)bt * 50 * NF;
        const float fn = P[(3 * f + 0) * NF + fr];
        const float gn = P[(3 * f + 1) * NF + fr];
        const float qn = P[(3 * f + 2) * NF + fr];

        float Q = __expf(-0.69314718f + qn * 3.4657359f);
        Q = clampf(Q, 0.1f, 100.0f);

        float lo, hi;
        int type;                        // 0 hp, 1 lp, 2 peak, 3 lowshelf, 4 highshelf
        if      (f == 0)  { lo = 20.0f;   hi = 500.0f;   type = 0; }
        else if (f == 15) { lo = 5000.0f; hi = 20000.0f; type = 1; }
        else if (f == 1)  { lo = 50.0f;   hi = 16000.0f; type = 3; }
        else if (f == 14) { lo = 50.0f;   hi = 16000.0f; type = 4; }
        else              { lo = 100.0f;  hi = 15000.0f; type = 2; }

        const float fc = __expf(__logf(lo) + fn * (__logf(hi) - __logf(lo)));
        float g_ = __tanf((float)M_PI * fc / 96000.0f);   // angle <= 0.655 rad
        g_ = clampf(g_, 1e-6f, 100.0f);
        const float gdb = -24.0f + 48.0f * gn;

        float a1, a2, a3, m0, m1, m2;
        if (type == 0 || type == 1) {
            const float k = 1.0f / Q;
            a1 = 1.0f / (1.0f + g_ * (g_ + k)); a2 = g_ * a1; a3 = g_ * a2;
            if (type == 0) { m0 = 1.0f; m1 = -k;   m2 = -1.0f; }
            else           { m0 = 0.0f; m1 = 0.0f; m2 = 1.0f;  }
        } else if (type == 2) {
            const float A = __expf(gdb * (2.30258509f / 40.0f));
            const float k = (gdb >= 0.0f) ? 1.0f / (Q * A) : A / Q;
            a1 = 1.0f / (1.0f + g_ * (g_ + k)); a2 = g_ * a1; a3 = g_ * a2;
            m0 = 1.0f; m1 = k * (A * A - 1.0f); m2 = 0.0f;
        } else {
            const float A  = __expf(gdb * (2.30258509f / 40.0f));
            const float sA = sqrtf(A);
            const float k  = 1.0f / Q;
            float gs;
            if (type == 3) gs = (gdb >= 0.0f) ? g_ / sA : g_ * sA;
            else           gs = (gdb >= 0.0f) ? g_ * sA : g_ / sA;
            a1 = 1.0f / (1.0f + gs * (gs + k)); a2 = gs * a1; a3 = gs * a2;
            if (type == 3) { m0 = 1.0f;  m1 = k * (A - 1.0f);      m2 = A * A - 1.0f; }
            else           { m0 = A * A; m1 = k * (1.0f - A) * A;  m2 = 1.0f - A * A; }
        }

        // affine per-sample form: s' = T s + b*x ; y = c0*s1 + c1*s2 + c2*x
        const float q2  = a2 * a2 + a3;
        const float t00 = 2.0f * a1 - 1.0f;
        const float t01 = -2.0f * a2;
        const float t10 = 2.0f * a1 * a2;
        const float t11 = 1.0f - 2.0f * q2;
        const float b0  = 2.0f * a2;
        const float b1  = 2.0f * q2;
        const float c0  = a1 * (m1 + m2 * a2);
        const float c1  = m2 * (1.0f - q2) - m1 * a2;
        const float c2  = m0 + m1 * a2 + m2 * q2;

        // T^16 by 4 squarings
        float u00 = t00, u01 = t01, u10 = t10, u11 = t11;
        #pragma unroll
        for (int i = 0; i < 4; i++) {
            const float n00 = u00 * u00 + u01 * u10;
            const float n01 = u00 * u01 + u01 * u11;
            const float n10 = u10 * u00 + u11 * u10;
            const float n11 = u10 * u01 + u11 * u11;
            u00 = n00; u01 = n01; u10 = n10; u11 = n11;
        }
        sc[f][fr][0] = t00; sc[f][fr][1] = t01; sc[f][fr][2] = t10; sc[f][fr][3] = t11;
        sc[f][fr][4] = b0;  sc[f][fr][5] = b1;  sc[f][fr][6] = c0;  sc[f][fr][7] = c1;
        sc[f][fr][8] = c2;  sc[f][fr][9] = u00; sc[f][fr][10] = u01; sc[f][fr][11] = u10;
        sc[f][fr][12] = u11;

        // continue squaring: T^16 -> T^1024 (6 more squarings)
        #pragma unroll
        for (int i = 0; i < 6; i++) {
            const float n00 = u00 * u00 + u01 * u10;
            const float n01 = u00 * u01 + u01 * u11;
            const float n10 = u10 * u00 + u11 * u10;
            const float n11 = u10 * u01 + u11 * u11;
            u00 = n00; u01 = n01; u10 = n10; u11 = n11;
        }
        const int lfr = fr - quarter * 6;
        if (lfr >= 0 && lfr < 6) {
            sMw[f][lfr] = make_float4(u00, u01, u10, u11);
        }
        // one more squaring: T^2048 (frame aggregate, ALL frames)
        {
            const float n00 = u00 * u00 + u01 * u10;
            const float n01 = u00 * u01 + u01 * u11;
            const float n10 = u10 * u00 + u11 * u10;
            const float n11 = u10 * u01 + u11 * u11;
            sT2048[f][fr] = make_float4(n00, n01, n10, n11);
        }
    }
    if (t >= 384 && t < 384 + 2 * NF) {
        const int idx = t - 384;
        const int which = idx / NF;     // 0 = in gain (row 48), 1 = out gain (row 49)
        const int fr    = idx % NF;
        const float* P = params + (size_t)bt * 50 * NF;
        const float p  = P[(48 + which) * NF + fr];
        const float db = -60.0f + 60.0f * p;
        sgain[which][fr] = __expf(db * (2.30258509f / 20.0f));
    }
    if (t < NB) sflag[t] = 0u;
    __syncthreads();

    // ------- prefix assembly (threads 0..15, one per stage) -------
    if (t < NB) {
        const int f = t;
        // exclusive wave prefixes P_w over local frames (Q = running product)
        float q00 = 1.0f, q01 = 0.0f, q10 = 0.0f, q11 = 1.0f;
        #pragma unroll
        for (int k = 0; k < 6; k++) {
            sPm[f][2 * k] = make_float4(q00, q01, q10, q11);
            const float4 mw = sMw[f][k];
            sPm[f][2 * k + 1] = make_float4(
                mw.x * q00 + mw.y * q10, mw.x * q01 + mw.y * q11,
                mw.z * q00 + mw.w * q10, mw.z * q01 + mw.w * q11);
            const float4 g = sT2048[f][quarter * 6 + k];
            const float n00 = g.x * q00 + g.y * q10;
            const float n01 = g.x * q01 + g.y * q11;
            const float n10 = g.z * q00 + g.w * q10;
            const float n11 = g.z * q01 + g.w * q11;
            q00 = n00; q01 = n01; q10 = n10; q11 = n11;
        }
        // pred-quarter fold matrices: W_{q-1}=I ; W_k = W_{k+1} * B_{k+1}
        if (quarter > 0) {
            float r00 = 1.0f, r01 = 0.0f, r10 = 0.0f, r11 = 1.0f;
            for (int k = quarter - 1; k >= 0; k--) {
                sWm[f][k] = make_float4(r00, r01, r10, r11);
                if (k > 0) {
                    float b00 = 1.0f, b01 = 0.0f, b10 = 0.0f, b11 = 1.0f;
                    #pragma unroll
                    for (int m = 0; m < 6; m++) {
                        const float4 g = sT2048[f][6 * k + m];
                        const float n00 = g.x * b00 + g.y * b10;
                        const float n01 = g.x * b01 + g.y * b11;
                        const float n10 = g.z * b00 + g.w * b10;
                        const float n11 = g.z * b01 + g.w * b11;
                        b00 = n00; b01 = n01; b10 = n10; b11 = n11;
                    }
                    const float n00 = r00 * b00 + r01 * b10;
                    const float n01 = r00 * b01 + r01 * b11;
                    const float n10 = r10 * b00 + r11 * b10;
                    const float n11 = r10 * b01 + r11 * b11;
                    r00 = n00; r01 = n01; r10 = n10; r11 = n11;
                }
            }
        }
    }
    __syncthreads();

    // ---------------- load chunk (with input gain) ----------------
    FOREACH_S(DECL_S)
    {
        const float ing = sgain[0][frame];
        const float* base = audio + (size_t)bt * S
                          + (size_t)(quarter * NCH + t) * CHUNK;
        float4 q;
        q = *(const float4*)(base +  0); s00 = q.x*ing; s01 = q.y*ing; s02 = q.z*ing; s03 = q.w*ing;
        q = *(const float4*)(base +  4); s04 = q.x*ing; s05 = q.y*ing; s06 = q.z*ing; s07 = q.w*ing;
        q = *(const float4*)(base +  8); s08 = q.x*ing; s09 = q.y*ing; s10 = q.z*ing; s11 = q.w*ing;
        q = *(const float4*)(base + 12); s12 = q.x*ing; s13 = q.y*ing; s14 = q.z*ing; s15 = q.w*ing;
    }

    // ---------------- 16 cascaded stages ----------------
    #pragma unroll 1
    for (int f = 0; f < NB; f++) {
        const float4 q0 = *(const float4*)&sc[f][frame][0];  // t00 t01 t10 t11
        const float4 q1 = *(const float4*)&sc[f][frame][4];  // b0 b1 c0 c1
        const float4 q2 = *(const float4*)&sc[f][frame][8];  // c2 M00 M01 M10
        const float  M11v = sc[f][frame][12];
        const float t00 = q0.x, t01 = q0.y, t10 = q0.z, t11 = q0.w;
        const float b0  = q1.x, b1  = q1.y, c0  = q1.z, c1  = q1.w;
        const float c2  = q2.x;

        // Phase A: zero-state run over own chunk -> affine constant
        float ic1 = 0.0f, ic2 = 0.0f;
        FOREACH_S(STEPA)

        // constants-only Kogge-Stone: wave-uniform M = T^16, M^d squared in place
        float Md00 = q2.y, Md01 = q2.z, Md10 = q2.w, Md11 = M11v;
        float Ac0 = ic1, Ac1 = ic2;
        #pragma unroll
        for (int d = 1; d < 64; d <<= 1) {
            const float lc0 = __shfl_up(Ac0, d);
            const float lc1 = __shfl_up(Ac1, d);
            if (lane >= d) {
                Ac0 = fmaf(Md00, lc0, fmaf(Md01, lc1, Ac0));
                Ac1 = fmaf(Md10, lc0, fmaf(Md11, lc1, Ac1));
            }
            const float n00 = Md00 * Md00 + Md01 * Md10;
            const float n01 = Md00 * Md01 + Md01 * Md11;
            const float n10 = Md10 * Md00 + Md11 * Md10;
            const float n11 = Md10 * Md01 + Md11 * Md11;
            Md00 = n00; Md01 = n01; Md10 = n10; Md11 = n11;
        }
        // Ac at lane 63 = wave aggregate constant

        const int buf = f & 1;
        if (lane == 63) sagg[buf][wave] = make_float2(Ac0, Ac1);

        // ce = exclusive constants -- issue pre-barrier, latency hides under it
        float ce0 = __shfl_up(Ac0, 1);
        float ce1 = __shfl_up(Ac1, 1);
        if (lane == 0) { ce0 = 0.0f; ce1 = 0.0f; }

        __syncthreads();   // the ONE barrier per round (sagg[buf] ready)

        const unsigned int tag = (unsigned int)(f + 1);
        unsigned int* stagebase = ws + ((size_t)(bt * NB + f) * NBLK) * 8;

        // -------- per-wave exclusive-prefix constant fold (parallel) --------
        float Pc0 = 0.0f, Pc1 = 0.0f;
        #pragma unroll
        for (int j = 0; j < NWAVE - 1; j++) {
            if (j < wave) {
                const float2 a = sagg[buf][j];
                const float4 mw = sMw[f][j >> 1];
                const float n0 = fmaf(mw.x, Pc0, fmaf(mw.y, Pc1, a.x));
                const float n1 = fmaf(mw.z, Pc0, fmaf(mw.w, Pc1, a.y));
                Pc0 = n0; Pc1 = n1;
            }
        }

        // -------- wave 11: block-inclusive from own registers -> publish ----
        if (wave == NWAVE - 1 && quarter < NBLK - 1 && lane == 63) {
            const float4 mw = sMw[f][(NWAVE - 1) >> 1];
            const float i0 = fmaf(mw.x, Pc0, fmaf(mw.y, Pc1, Ac0));
            const float i1 = fmaf(mw.z, Pc0, fmaf(mw.w, Pc1, Ac1));
            unsigned int* slot = stagebase + quarter * 8;
            float* dp = (float*)(slot + 1);
            __hip_atomic_store(&dp[0], i0, __ATOMIC_RELAXED, __HIP_MEMORY_SCOPE_AGENT);
            __hip_atomic_store(&dp[1], i1, __ATOMIC_RELAXED, __HIP_MEMORY_SCOPE_AGENT);
            __hip_atomic_store(slot, tag, __ATOMIC_RELEASE, __HIP_MEMORY_SCOPE_AGENT);
        }

        // -------- block incoming state S0 (single poller: wave 0) -----------
        float S0x = 0.0f, S0y = 0.0f;
        if (quarter > 0) {
            if (wave == 0) {
                float ux = 0.0f, uy = 0.0f;
                if (lane < quarter) {
                    unsigned int* slot = stagebase + lane * 8;
                    while (__hip_atomic_load(slot, __ATOMIC_ACQUIRE, __HIP_MEMORY_SCOPE_AGENT) != tag) {
                        __builtin_amdgcn_s_sleep(1);
                    }
                    const float* dp = (const float*)(slot + 1);
                    const float cx = __hip_atomic_load(&dp[0], __ATOMIC_RELAXED, __HIP_MEMORY_SCOPE_AGENT);
                    const float cy = __hip_atomic_load(&dp[1], __ATOMIC_RELAXED, __HIP_MEMORY_SCOPE_AGENT);
                    const float4 w = sWm[f][lane];
                    ux = fmaf(w.x, cx, w.y * cy);
                    uy = fmaf(w.z, cx, w.w * cy);
                }
                S0x = __shfl(ux, 0);
                S0y = __shfl(uy, 0);
                if (quarter > 1) { S0x += __shfl(ux, 1); S0y += __shfl(uy, 1); }
                if (quarter > 2) { S0x += __shfl(ux, 2); S0y += __shfl(uy, 2); }
                if (lane == 0) {
                    sS0 = make_float2(S0x, S0y);
                    __hip_atomic_store(&sflag[f], tag, __ATOMIC_RELEASE,
                                       __HIP_MEMORY_SCOPE_WORKGROUP);
                }
            } else {
                while (__hip_atomic_load(&sflag[f], __ATOMIC_ACQUIRE,
                                         __HIP_MEMORY_SCOPE_WORKGROUP) != tag)
                    __builtin_amdgcn_s_sleep(1);
                const float2 sb = sS0;
                S0x = sb.x; S0y = sb.y;
            }
        }

        // -------- incoming wave state v = P_w * S0 + Pc_w (local compute) ---
        const float4 pm = sPm[f][wave];
        const float vx = fmaf(pm.x, S0x, fmaf(pm.y, S0y, Pc0));
        const float vy = fmaf(pm.z, S0x, fmaf(pm.w, S0y, Pc1));

        // -------- distribute: ic = M^lane * v + ce (binexp, reg squaring) ---
        float w0 = vx, w1 = vy;
        float p00 = q2.y, p01 = q2.z, p10 = q2.w, p11 = M11v;
        #pragma unroll
        for (int b = 0; b < 6; b++) {
            if (lane & (1 << b)) {
                const float nw0 = fmaf(p00, w0, p01 * w1);
                const float nw1 = fmaf(p10, w0, p11 * w1);
                w0 = nw0; w1 = nw1;
            }
            if (b < 5) {
                const float n00 = p00 * p00 + p01 * p10;
                const float n01 = p00 * p01 + p01 * p11;
                const float n10 = p10 * p00 + p11 * p10;
                const float n11 = p10 * p01 + p11 * p11;
                p00 = n00; p01 = n01; p10 = n10; p11 = n11;
            }
        }
        float ic1r = w0 + ce0;
        float ic2r = w1 + ce1;
        ic1 = ic1r; ic2 = ic2r;

        // Phase C: true run from incoming state, write outputs in place
        FOREACH_S(STEPC)
    }

    // ---------------- store (with output gain) ----------------
    {
        const float og = sgain[1][frame];
        float* base = out + (size_t)bt * S + (size_t)(quarter * NCH + t) * CHUNK;
        float4 q;
        q.x = s00*og; q.y = s01*og; q.z = s02*og; q.w = s03*og; *(float4*)(base +  0) = q;
        q.x = s04*og; q.y = s05*og; q.z = s06*og; q.w = s07*og; *(float4*)(base +  4) = q;
        q.x = s08*og; q.y = s09*og; q.z = s10*og; q.w = s11*og; *(float4*)(base +  8) = q;
        q.x = s12*og; q.y = s13*og; q.z = s14*og; q.w = s15*og; *(float4*)(base + 12) = q;
    }
}

extern "C" void kernel_launch(void* const* d_in, const int* in_sizes, int n_in,
                              void* d_out, int out_size, void* d_ws, size_t ws_size,
                              hipStream_t stream)
{
    const float* audio  = (const float*)d_in[0];
    const float* params = (const float*)d_in[1];
    float* out = (float*)d_out;
    unsigned int* ws = (unsigned int*)d_ws;
    biquad_chain_kernel<<<NBLK * NBATCH, NCH, 0, stream>>>(audio, params, out, ws);
}